// Round 3
// baseline (214.803 us; speedup 1.0000x reference)
//
#include <hip/hip_runtime.h>
#include <hip/hip_bf16.h>
#include <hip/hip_fp16.h>

#define BS 8
#define C  256
#define N  9216
#define E  9215
#define MAXD 128               // off[] bins; actual depth <= 64 (6 doubling iters)
#define NARROW 64              // level-size threshold for single-wave processing
#define CPG 16                 // channels per weights block (R3: 8->16)
#define NG  (C / CPG)          // 16 weight blocks per batch
#define NBLK (BS + BS * NG)    // 8 hybrid + 128 weight = 136 blocks <= 256 CUs
                               // (1 block/CU @149.5KB LDS -> ALL resident: spin-wait is deadlock-free)

typedef __attribute__((address_space(1))) const void GVoid;
typedef __attribute__((address_space(3))) void LVoid;

// ---------------------------------------------------------------------------
// Single fused kernel.
//   blocks [0,8)    HYBRID: per-batch level schedule (P/U aliased into V) ->
//                   scatter ts into TSW[].x -> V init -> spin on flagG[b] ->
//                   fill TSW[].y = exp(-zeta*dist) via agent-scope loads ->
//                   LDS-resident up/down DP -> out.  No uparr/lvlOff globals.
//   blocks [8,136)  WEIGHTS: (batch, 16-channel group). Double-buffered async
//                   global_load_lds staging of 36KB channel rows into the two
//                   halves of V; per-edge sq-dist accumulated in registers;
//                   one atomicAdd per edge into distG; release flagG[b].
// Producer/consumer: weight blocks __threadfence + agent-scope flag add;
// hybrid reads distG with agent-scope atomic loads (coherent, bypasses L1).
// ---------------------------------------------------------------------------
__global__ __launch_bounds__(1024) void fused_kernel(const float* __restrict__ feat,
                                                     const float* __restrict__ emb,
                                                     const int* __restrict__ tree,
                                                     float* __restrict__ distG,
                                                     int* __restrict__ flagG,
                                                     float* __restrict__ out) {
    __shared__ float2 V[N];           // hybrid: P|U overlay then (F,G); weights: 2x36KB row bufs
    __shared__ int2 TSW[N];           // (child|parent<<16, w bits), level order
    __shared__ int cnt8[MAXD * 8];    // 8 sub-counters per level
    __shared__ int tot[MAXD];
    __shared__ int sc1[MAXD];
    __shared__ int off[MAXD + 1];
    __shared__ int meta[3];           // maxd, loE, hiS
    __shared__ int maxd_sh;
    const int tid = threadIdx.x;

    if (blockIdx.x >= BS) {
        // ---- weights role ----
        const int wb = blockIdx.x - BS;
        const int b  = wb & 7;            // batch fastest -> spreads XCD traffic
        const int c0 = (wb >> 3) * CPG;
        const int wave = tid >> 6, lane = tid & 63;

        float* cur = (float*)V;           // two 36 KB halves of V
        float* nxt = (float*)V + N;

        int se[9];
        #pragma unroll
        for (int k = 0; k < 9; ++k) {
            int e = tid + k * 1024;
            se[k] = (e < E) ? tree[((size_t)b * E + e) * 2] : 0;
        }
        float acc[9];
        #pragma unroll
        for (int k = 0; k < 9; ++k) acc[k] = 0.f;

        // async stage: 36 KB row = 36 chunks of 1 KB (64 lanes x 16 B), 16 waves
        const float* rowbase = emb + ((size_t)b * C + c0) * N;
        for (int chk = wave; chk < 36; chk += 16)
            __builtin_amdgcn_global_load_lds(
                (GVoid*)(rowbase + chk * 256 + lane * 4),
                (LVoid*)(cur + chk * 256), 16, 0, 0);
        __syncthreads();                                 // ch0 ready

        for (int cc = 0; cc < CPG; ++cc) {
            if (cc + 1 < CPG) {                          // async prefetch next channel
                const float* src = rowbase + (size_t)(cc + 1) * N;
                for (int chk = wave; chk < 36; chk += 16)
                    __builtin_amdgcn_global_load_lds(
                        (GVoid*)(src + chk * 256 + lane * 4),
                        (LVoid*)(nxt + chk * 256), 16, 0, 0);
            }
            #pragma unroll
            for (int k = 0; k < 9; ++k) {
                int e = tid + k * 1024;
                if (e < E) {
                    float d = cur[se[k]] - cur[e + 1];   // tgt = e+1 (children=arange)
                    acc[k] += d * d;
                }
            }
            __syncthreads();                             // nxt staged + cur reads done
            float* t = cur; cur = nxt; nxt = t;
        }
        #pragma unroll
        for (int k = 0; k < 9; ++k) {
            int e = tid + k * 1024;
            if (e < E) atomicAdd(&distG[(size_t)b * N + e], acc[k]);
        }
        __syncthreads();                                 // all lanes' atomics issued+drained
        __threadfence();                                 // release distG before flag
        if (tid == 0)
            __hip_atomic_fetch_add(&flagG[b], 1, __ATOMIC_RELEASE,
                                   __HIP_MEMORY_SCOPE_AGENT);
        return;
    }

    // ---- hybrid role: levels + DP for batch b ----
    const int b = blockIdx.x;
    const int* tb = tree + b * E * 2;
    int* P = (int*)V;                 // levels overlay in V space
    int* U = ((int*)V) + N;

    for (int t = tid; t < N; t += 1024)
        P[t] = (t == 0) ? 0 : (tb[(t - 1) * 2] | (1 << 16));
    for (int i = tid; i < MAXD * 8; i += 1024) cnt8[i] = 0;
    if (tid == 0) maxd_sh = 1;
    __syncthreads();

    // packed pointer doubling P<->U with converged-node skip (depth <= 64)
    for (int r = 0; r < 3; ++r) {
        for (int t = tid; t < N; t += 1024) {
            int p = P[t];
            int a = p & 0xffff;
            if (a == 0) U[t] = p;
            else {
                int pa = P[a];
                U[t] = (pa & 0xffff) | (((p >> 16) + (pa >> 16)) << 16);
            }
        }
        __syncthreads();
        for (int t = tid; t < N; t += 1024) {
            int p = U[t];
            int a = p & 0xffff;
            if (a == 0) P[t] = p;
            else {
                int pa = U[a];
                P[t] = (pa & 0xffff) | (((p >> 16) + (pa >> 16)) << 16);
            }
        }
        __syncthreads();
    }

    // depth histogram into 8 sub-counters per level
    for (int t = 1 + tid; t < N; t += 1024) {
        int d = P[t] >> 16;
        atomicAdd(&cnt8[d * 8 + (tid >> 7)], 1);
    }
    __syncthreads();

    // sub-prefix within each level + totals
    for (int d = tid; d < MAXD; d += 1024) {
        int s = 0;
        #pragma unroll
        for (int k = 0; k < 8; ++k) {
            int v = cnt8[d * 8 + k];
            cnt8[d * 8 + k] = s;
            s += v;
        }
        tot[d] = s;
        if (s > 0) atomicMax(&maxd_sh, d);
    }
    __syncthreads();

    // Hillis-Steele inclusive scan over level totals -> off
    {
        int* src = tot; int* dst = sc1;
        for (int step = 1; step < MAXD; step <<= 1) {
            for (int d = tid; d < MAXD; d += 1024)
                dst[d] = src[d] + ((d >= step) ? src[d - step] : 0);
            __syncthreads();
            int* tmp = src; src = dst; dst = tmp;
        }
        for (int d = tid; d < MAXD; d += 1024) off[d + 1] = src[d];
        if (tid == 0) off[0] = 0;
    }
    __syncthreads();

    // narrow/wide markers + counting-sort scatter of ts into TSW[].x
    if (tid == 0) {
        int md = maxd_sh;
        int lo = 0;
        while (lo < md && off[lo + 2] - off[lo + 1] <= NARROW) ++lo;
        int hi = md + 1;
        while (hi > lo + 1 && off[hi] - off[hi - 1] <= NARROW) --hi;
        meta[0] = md; meta[1] = lo; meta[2] = hi;
    }
    for (int t = 1 + tid; t < N; t += 1024) {
        int d = P[t] >> 16;
        int idx = atomicAdd(&cnt8[d * 8 + (tid >> 7)], 1);
        int slot = off[d] + idx;
        int p = tb[(t - 1) * 2];          // L2-hot re-read
        TSW[slot].x = t | (p << 16);
    }
    __syncthreads();                       // P/U dead from here

    // V init overlaps weight blocks still running
    for (int i = tid; i < N; i += 1024)
        V[i] = make_float2(feat[b * N + i], 1.0f);

    // wait for all NG weight blocks of this batch
    if (tid == 0) {
        while (__hip_atomic_load(&flagG[b], __ATOMIC_ACQUIRE,
                                 __HIP_MEMORY_SCOPE_AGENT) < NG)
            __builtin_amdgcn_s_sleep(8);
    }
    __syncthreads();

    // fill weights: agent-scope loads (coherent vs other-XCD atomics)
    const float* dG = distG + b * N;
    for (int i = tid; i < E; i += 1024) {
        int ts = TSW[i].x;
        float ds = __hip_atomic_load(&dG[(ts & 0xffff) - 1], __ATOMIC_RELAXED,
                                     __HIP_MEMORY_SCOPE_AGENT);
        TSW[i].y = __float_as_int(__expf(-0.01f * ds));
    }
    __syncthreads();
    const int maxd = meta[0], loE = meta[1], hiS = meta[2];

    // ---- up pass (deepest level first) ----
    if (tid < 64) {                                  // narrow deep tail: wave 0
        for (int lev = maxd; lev >= hiS; --lev) {
            int s0 = off[lev], s1 = off[lev + 1];
            for (int i = s0 + tid; i < s1; i += 64) {
                int2 ew = TSW[i];
                int t = ew.x & 0xffff, p = ew.x >> 16;
                float w = __int_as_float(ew.y);
                float2 vt = V[t];
                atomicAdd(&V[p].x, w * vt.x);
                atomicAdd(&V[p].y, w * vt.y);
            }
            __threadfence_block();
        }
    }
    __syncthreads();
    for (int lev = hiS - 1; lev > loE; --lev) {      // wide middle: all waves
        int s0 = off[lev], s1 = off[lev + 1];
        for (int i = s0 + tid; i < s1; i += 1024) {
            int2 ew = TSW[i];
            int t = ew.x & 0xffff, p = ew.x >> 16;
            float w = __int_as_float(ew.y);
            float2 vt = V[t];
            atomicAdd(&V[p].x, w * vt.x);
            atomicAdd(&V[p].y, w * vt.y);
        }
        __syncthreads();
    }
    if (tid < 64) {                                  // narrow top: wave 0
        for (int lev = loE; lev >= 1; --lev) {
            int s0 = off[lev], s1 = off[lev + 1];
            for (int i = s0 + tid; i < s1; i += 64) {
                int2 ew = TSW[i];
                int t = ew.x & 0xffff, p = ew.x >> 16;
                float w = __int_as_float(ew.y);
                float2 vt = V[t];
                atomicAdd(&V[p].x, w * vt.x);
                atomicAdd(&V[p].y, w * vt.y);
            }
            __threadfence_block();
        }
    }
    __syncthreads();

    // ---- down pass (root to leaf) ----
    if (tid < 64) {                                  // narrow top: wave 0
        for (int lev = 1; lev <= loE; ++lev) {
            int s0 = off[lev], s1 = off[lev + 1];
            for (int i = s0 + tid; i < s1; i += 64) {
                int2 ew = TSW[i];
                int t = ew.x & 0xffff, s = ew.x >> 16;
                float w = __int_as_float(ew.y);
                float2 vs = V[s], vt = V[t];
                float c = 1.f - w * w;
                V[t] = make_float2(w * vs.x + c * vt.x, w * vs.y + c * vt.y);
            }
            __threadfence_block();
        }
    }
    __syncthreads();
    for (int lev = loE + 1; lev < hiS; ++lev) {      // wide middle: all waves
        int s0 = off[lev], s1 = off[lev + 1];
        for (int i = s0 + tid; i < s1; i += 1024) {
            int2 ew = TSW[i];
            int t = ew.x & 0xffff, s = ew.x >> 16;
            float w = __int_as_float(ew.y);
            float2 vs = V[s], vt = V[t];
            float c = 1.f - w * w;
            V[t] = make_float2(w * vs.x + c * vt.x, w * vs.y + c * vt.y);
        }
        __syncthreads();
    }
    if (tid < 64) {                                  // narrow deep tail: wave 0
        for (int lev = hiS; lev <= maxd; ++lev) {
            int s0 = off[lev], s1 = off[lev + 1];
            for (int i = s0 + tid; i < s1; i += 64) {
                int2 ew = TSW[i];
                int t = ew.x & 0xffff, s = ew.x >> 16;
                float w = __int_as_float(ew.y);
                float2 vs = V[s], vt = V[t];
                float c = 1.f - w * w;
                V[t] = make_float2(w * vs.x + c * vt.x, w * vs.y + c * vt.y);
            }
            __threadfence_block();
        }
    }
    __syncthreads();

    for (int i = tid; i < N; i += 1024) {
        float2 v = V[i];
        out[b * N + i] = v.x / v.y;
    }
}

extern "C" void kernel_launch(void* const* d_in, const int* in_sizes, int n_in,
                              void* d_out, int out_size, void* d_ws, size_t ws_size,
                              hipStream_t stream) {
    const float* feat = (const float*)d_in[0];   // [8,1,96,96]
    const float* emb  = (const float*)d_in[1];   // [8,256,96,96]
    const int*   tree = (const int*)d_in[2];     // [8,9215,2]
    float* out = (float*)d_out;                  // [8,1,96,96]

    const size_t BN = (size_t)BS * N;
    float* distG = (float*)d_ws;                             // BN f32 (edge sq-dist)
    int*   flagG = (int*)((char*)d_ws + BN * 4);             // BS i32 done-flags

    hipMemsetAsync(d_ws, 0, BN * 4 + 256, stream);           // distG + flags, capture-legal
    fused_kernel<<<NBLK, 1024, 0, stream>>>(feat, emb, tree, distG, flagG, out);
}